// Round 20
// baseline (139.135 us; speedup 1.0000x reference)
//
#include <hip/hip_runtime.h>
#include <cstdint>

#define BB 16
#define MM 128
#define TT 12000
constexpr int BT = BB * TT; // 192000

// Q4-interleaved scan layout: element (row b, pos t), t=4g+j lives at
// q[(g*16 + b)*4 + j]. SB = 4 groups = 1024 B (16 elems/row).
// Chunk = 28 SBs = 28672 B = 7168 floats = 1792 float4s.
#define CH_SB 28
#define CH_F4 1792
#define CH_BYTES 28672
#define NCHUNK 27   // 27*28 = 756 SBs >= 750 real SBs

// K1: per-column stats over the M axis, sequential in m (reference order).
// anti-fma via `#pragma clang fp contract(off)` (proven round 13).
__global__ void k1_colstats(const float* __restrict__ mel,
                            float* __restrict__ ssq,
                            float* __restrict__ dotv,
                            float* __restrict__ cmean,
                            unsigned int* __restrict__ counts) {
    if (blockIdx.x == 0 && blockIdx.y == 0 && threadIdx.x < 8)
        counts[threadIdx.x] = 0u;
    const int b = blockIdx.y;
    const int t = blockIdx.x * blockDim.x + threadIdx.x;
    if (t >= TT) return;
    const float* base = mel + (size_t)b * MM * TT;
    float accd = 0.f, accq = 0.f, accs = 0.f;
    {
#pragma clang fp contract(off)
        for (int m = 0; m < MM; ++m) {
            const float* rowp = base + (size_t)m * TT;
            float cur = rowp[t];
            float prev = (t > 0) ? rowp[t - 1] : 0.f;
            accd += prev * cur;
            accq += cur * cur;
            accs += cur;
        }
    }
    size_t i = (size_t)b * TT + t;
    ssq[i] = accq; dotv[i] = accd; cmean[i] = accs * (1.0f / MM);
}

// kA: temporal = 1 - std(smooth, ddof=1). Row staged to LDS once.
__global__ void kA_temporal(const float* __restrict__ cmean,
                            float* __restrict__ temporal) {
    const int b = blockIdx.x;
    const int tid = threadIdx.x;
    __shared__ __align__(16) float row_s[TT];
    __shared__ float red[256];
    __shared__ float mean_s;
    const float4* c4 = (const float4*)(cmean + (size_t)b * TT);
    float4* r4 = (float4*)row_s;
    for (int i = tid; i < TT / 4; i += 256) r4[i] = c4[i];
    __syncthreads();

    float s = 0.f;
    for (int t = tid; t < TT; t += 256) {
        float v = 0.f;
        int lo = t - 2 < 0 ? 0 : t - 2;
        int hi = t + 2 >= TT ? TT - 1 : t + 2;
        for (int j = lo; j <= hi; ++j) v += row_s[j];
        s += v / 5.0f;
    }
    red[tid] = s; __syncthreads();
    for (int o = 128; o > 0; o >>= 1) {
        if (tid < o) red[tid] += red[tid + o];
        __syncthreads();
    }
    if (tid == 0) mean_s = red[0] / (float)TT;
    __syncthreads();
    float mean = mean_s;
    float ss = 0.f;
    for (int t = tid; t < TT; t += 256) {
        float v = 0.f;
        int lo = t - 2 < 0 ? 0 : t - 2;
        int hi = t + 2 >= TT ? TT - 1 : t + 2;
        for (int j = lo; j <= hi; ++j) v += row_s[j];
        float sm = v / 5.0f - mean;
        ss += sm * sm;
    }
    red[tid] = ss; __syncthreads();
    for (int o = 128; o > 0; o >>= 1) {
        if (tid < o) red[tid] += red[tid + o];
        __syncthreads();
    }
    if (tid == 0) {
        float var = red[0] / (float)(TT - 1);
        temporal[b] = 1.0f - sqrtf(var);
    }
}

// kB: cons — same arithmetic as the passing version; additionally writes
// the Q4-interleaved copy for the scan (same value, extra store only).
__global__ void kB_cons(const float* __restrict__ ssq,
                        const float* __restrict__ dotv,
                        const float* __restrict__ spec,
                        const float* __restrict__ temporal,
                        const float* __restrict__ wraw,
                        float* __restrict__ cons,
                        float* __restrict__ consq) {
    const int idx = blockIdx.x * 256 + threadIdx.x;
    const int b = idx / TT;
    const int t = idx - b * TT;
    float x0 = wraw[0], x1 = wraw[1], x2 = wraw[2];
    float mx = fmaxf(x0, fmaxf(x1, x2));
    float e0 = expf(x0 - mx), e1 = expf(x1 - mx), e2 = expf(x2 - mx);
    float es = (e0 + e1) + e2;
    float w0 = e0 / es, w1 = e1 / es, w2 = e2 / es;
    float mel_sim, spec_sim;
    if (t == 0) { mel_sim = 0.f; spec_sim = 1.f; }
    else {
        float na = fmaxf(sqrtf(ssq[idx - 1]), 1e-8f);
        float nb = fmaxf(sqrtf(ssq[idx]),     1e-8f);
        float den = na * nb; asm volatile("" : "+v"(den));
        mel_sim = dotv[idx] / den;
        float d = fabsf(spec[idx] - spec[idx - 1]);
        spec_sim = 1.0f / (1.0f + d);
    }
    float pa = w0 * mel_sim;     asm volatile("" : "+v"(pa));
    float pb = w1 * spec_sim;    asm volatile("" : "+v"(pb));
    float pc = w2 * temporal[b]; asm volatile("" : "+v"(pc));
    float c = (pa + pb) + pc;
    cons[idx] = c;
    consq[((t >> 2) * 16 + b) * 4 + (t & 3)] = c;
}

// One SB (16 elems, 16 lanes lockstep): counted pure-read lgkm wait
// (ring of 4 SBs -> 16 reads outstanding, drain oldest 4), 16 chained
// adds (bitwise reference order, carry in/out via %0, snapshot BEFORE the
// prefetch reads — round-5 WAR discipline), 4 CS stores to global
// (fire-and-forget vmcnt), 4 prefetch ds_reads 4 SBs ahead.
#define SB16(a0,a1,a2,a3, b0,b1,b2,b3, c0,c1,c2,c3, d0,d1,d2,d3, S0,S1,S2,S3, P0,P1,P2,P3) \
    "s_waitcnt lgkmcnt(12)\n\t" \
    "v_add_f32 v" a0 ", %0, v" a0 "\n\t" \
    "v_add_f32 v" a1 ", v" a0 ", v" a1 "\n\t" \
    "v_add_f32 v" a2 ", v" a1 ", v" a2 "\n\t" \
    "v_add_f32 v" a3 ", v" a2 ", v" a3 "\n\t" \
    "v_add_f32 v" b0 ", v" a3 ", v" b0 "\n\t" \
    "v_add_f32 v" b1 ", v" b0 ", v" b1 "\n\t" \
    "v_add_f32 v" b2 ", v" b1 ", v" b2 "\n\t" \
    "v_add_f32 v" b3 ", v" b2 ", v" b3 "\n\t" \
    "v_add_f32 v" c0 ", v" b3 ", v" c0 "\n\t" \
    "v_add_f32 v" c1 ", v" c0 ", v" c1 "\n\t" \
    "v_add_f32 v" c2 ", v" c1 ", v" c2 "\n\t" \
    "v_add_f32 v" c3 ", v" c2 ", v" c3 "\n\t" \
    "v_add_f32 v" d0 ", v" c3 ", v" d0 "\n\t" \
    "v_add_f32 v" d1 ", v" d0 ", v" d1 "\n\t" \
    "v_add_f32 v" d2 ", v" d1 ", v" d2 "\n\t" \
    "v_add_f32 v" d3 ", v" d2 ", v" d3 "\n\t" \
    "v_mov_b32 %0, v" d3 "\n\t" \
    "global_store_dwordx4 v40, v[" a0 ":" a3 "], %1 offset:" S0 "\n\t" \
    "global_store_dwordx4 v40, v[" b0 ":" b3 "], %1 offset:" S1 "\n\t" \
    "global_store_dwordx4 v40, v[" c0 ":" c3 "], %1 offset:" S2 "\n\t" \
    "global_store_dwordx4 v40, v[" d0 ":" d3 "], %1 offset:" S3 "\n\t" \
    "ds_read_b128 v[" a0 ":" a3 "], v41 offset:" P0 "\n\t" \
    "ds_read_b128 v[" b0 ":" b3 "], v41 offset:" P1 "\n\t" \
    "ds_read_b128 v[" c0 ":" c3 "], v41 offset:" P2 "\n\t" \
    "ds_read_b128 v[" d0 ":" d3 "], v41 offset:" P3 "\n\t"

// kC: chunked double-buffered 16-lane SIMT scan. Per chunk c: waves 1-3
// stage chunk c+1 (global->LDS, 28 KB) while wave-0 lanes 0-15 scan
// chunk c from LDS (pure-read lgkm ring) storing CS to global Q4.
// Carry crosses chunks via a "+v" operand. SBs 750..755 are past every
// row's end (garbage in, garbage stored past the real CS region).
__global__ void __launch_bounds__(256)
kC_scan16(const float* __restrict__ consq,
          float* __restrict__ CSq) {
    const int tid = threadIdx.x;
    __shared__ __align__(16) float bufA[CH_F4 * 4];
    __shared__ __align__(16) float bufB[CH_F4 * 4];
    float4* bA4 = (float4*)bufA;
    float4* bB4 = (float4*)bufB;
    const float4* src4 = (const float4*)consq;

    // stage chunk 0 (all threads)
    for (int i = tid; i < CH_F4; i += 256) bA4[i] = src4[i];
    __syncthreads();

    float carry = 0.f;
    for (int c = 0; c < NCHUNK; ++c) {
        if (tid >= 64 && c + 1 < NCHUNK) {
            const float4* s4 = src4 + (size_t)(c + 1) * CH_F4;
            float4* d4 = ((c + 1) & 1) ? bB4 : bA4;
            for (int i = tid - 64; i < CH_F4; i += 192) d4[i] = s4[i];
        }
        if (tid < BB) {
            uint32_t lds_addr = (uint32_t)(uintptr_t)((c & 1) ? bufB : bufA)
                              + (uint32_t)(tid * 16);
            uint32_t goff = (uint32_t)(c * CH_BYTES + tid * 16);
            asm volatile(
                "v_mov_b32 v40, %3\n\t"
                "v_mov_b32 v41, %2\n\t"
                // prologue: prefetch SBs 0..3 of this chunk (16 reads)
                "ds_read_b128 v[48:51],   v41 offset:0\n\t"
                "ds_read_b128 v[52:55],   v41 offset:256\n\t"
                "ds_read_b128 v[56:59],   v41 offset:512\n\t"
                "ds_read_b128 v[60:63],   v41 offset:768\n\t"
                "ds_read_b128 v[64:67],   v41 offset:1024\n\t"
                "ds_read_b128 v[68:71],   v41 offset:1280\n\t"
                "ds_read_b128 v[72:75],   v41 offset:1536\n\t"
                "ds_read_b128 v[76:79],   v41 offset:1792\n\t"
                "ds_read_b128 v[80:83],   v41 offset:2048\n\t"
                "ds_read_b128 v[84:87],   v41 offset:2304\n\t"
                "ds_read_b128 v[88:91],   v41 offset:2560\n\t"
                "ds_read_b128 v[92:95],   v41 offset:2816\n\t"
                "ds_read_b128 v[96:99],   v41 offset:3072\n\t"
                "ds_read_b128 v[100:103], v41 offset:3328\n\t"
                "ds_read_b128 v[104:107], v41 offset:3584\n\t"
                "ds_read_b128 v[108:111], v41 offset:3840\n\t"
                "s_mov_b32 s20, 7\n\t"   // 7 iters x 4 SBs = 28 SBs
                "3:\n\t"
                SB16("48","49","50","51", "52","53","54","55",
                     "56","57","58","59", "60","61","62","63",
                     "0","256","512","768", "4096","4352","4608","4864")
                SB16("64","65","66","67", "68","69","70","71",
                     "72","73","74","75", "76","77","78","79",
                     "1024","1280","1536","1792", "5120","5376","5632","5888")
                SB16("80","81","82","83", "84","85","86","87",
                     "88","89","90","91", "92","93","94","95",
                     "2048","2304","2560","2816", "6144","6400","6656","6912")
                SB16("96","97","98","99", "100","101","102","103",
                     "104","105","106","107", "108","109","110","111",
                     "3072","3328","3584","3840", "7168","7424","7680","7936")
                "v_add_u32 v40, 0x1000, v40\n\t"
                "v_add_u32 v41, 0x1000, v41\n\t"
                "s_sub_u32 s20, s20, 1\n\t"
                "s_cmp_lg_u32 s20, 0\n\t"
                "s_cbranch_scc1 3b\n\t"
                // drain: tail prefetches (LDS-OOB, discarded) + stores
                "s_waitcnt vmcnt(0) lgkmcnt(0)\n\t"
                : "+v"(carry)
                : "s"(CSq), "v"(lds_addr), "v"(goff)
                : "v40", "v41",
                  "v48", "v49", "v50", "v51", "v52", "v53", "v54", "v55",
                  "v56", "v57", "v58", "v59", "v60", "v61", "v62", "v63",
                  "v64", "v65", "v66", "v67", "v68", "v69", "v70", "v71",
                  "v72", "v73", "v74", "v75", "v76", "v77", "v78", "v79",
                  "v80", "v81", "v82", "v83", "v84", "v85", "v86", "v87",
                  "v88", "v89", "v90", "v91", "v92", "v93", "v94", "v95",
                  "v96", "v97", "v98", "v99", "v100", "v101", "v102", "v103",
                  "v104", "v105", "v106", "v107", "v108", "v109", "v110", "v111",
                  "s20", "scc", "memory");
        }
        __syncthreads();
    }
}

// kD: candbits + local/step + 5-iter never-done sim. CS read from the
// Q4-interleaved buffer (same values bitwise). Flags instead of counts.
__global__ void kD_prepare(const float* __restrict__ cons,
                           const float* __restrict__ CSq,
                           const float* __restrict__ init,
                           float* __restrict__ stepv,
                           float* __restrict__ candf,
                           unsigned int* __restrict__ counts) {
    const int idx = blockIdx.x * 256 + threadIdx.x;
    const int b = idx / TT;
    const int t = idx - b * TT;
    __shared__ unsigned sflag[5];
    if (threadIdx.x < 5) sflag[threadIdx.x] = 0u;
    __syncthreads();

    int lo = t - 2; if (lo < 0) lo = 0;
    int hi = t + 3; if (hi > TT) hi = TT;
    int uh = hi - 1;
    float csH = CSq[((uh >> 2) * 16 + b) * 4 + (uh & 3)];
    float csL = 0.f;
    if (lo > 0) {
        int ul = lo - 1;
        csL = CSq[((ul >> 2) * 16 + b) * 4 + (ul & 3)];
    }
    float local = (csH - csL) / (float)(hi - lo);
    float dir = (local > 0.7f) ? -0.1f : ((local < 0.4f) ? 0.1f : 0.0f);
    bool interior = (t >= 1) && (t <= TT - 2);
    float step = interior ? dir : 0.0f;
    float g = (t == 0) ? 0.f : fabsf(cons[idx] - cons[idx - 1]);
    float cand = (g > 0.15f) ? 1.f : 0.f;
    float r = init[idx];
    bool nz[5];
#pragma unroll
    for (int j = 0; j < 5; ++j) {
        float adj = (fmaxf(cand, r) > 0.5f) ? step : 0.0f;
        nz[j] = (adj != 0.0f);
        r = fminf(fmaxf(r + adj, 0.0f), 1.0f);
    }
    stepv[idx] = step; candf[idx] = cand;
    const int lane = threadIdx.x & 63;
#pragma unroll
    for (int j = 0; j < 5; ++j) {
        unsigned long long mb = __ballot(nz[j]);
        if (lane == 0 && mb) atomicOr(&sflag[j], 1u);   // LDS-scope, cheap
    }
    __syncthreads();
    if (threadIdx.x < 5 && sflag[threadIdx.x]) counts[threadIdx.x] = 1u;
}

// K_final: freeze at the first iteration whose adjustment flag is 0.
__global__ void k_final(const float* __restrict__ init,
                        const float* __restrict__ stepv,
                        const float* __restrict__ candf,
                        const unsigned int* __restrict__ counts,
                        float* __restrict__ outp) {
    const int idx = blockIdx.x * 256 + threadIdx.x;
    float r = init[idx];
    float step = stepv[idx];
    float cand = candf[idx];
    unsigned c[5];
#pragma unroll
    for (int j = 0; j < 5; ++j) c[j] = counts[j];
#pragma unroll
    for (int j = 0; j < 5; ++j) {
        if (c[j] == 0u) break;
        float adj = (fmaxf(cand, r) > 0.5f) ? step : 0.0f;
        r = fminf(fmaxf(r + adj, 0.0f), 1.0f);
    }
    outp[idx] = r;
}

extern "C" void kernel_launch(void* const* d_in, const int* in_sizes, int n_in,
                              void* d_out, int out_size, void* d_ws, size_t ws_size,
                              hipStream_t stream) {
    const float* mel  = (const float*)d_in[0];
    const float* spec = (const float*)d_in[1];
    const float* init = (const float*)d_in[2];
    const float* wts  = (const float*)d_in[3];

    float* ws = (float*)d_ws;
    float* ssq   = ws;                 // 192000
    float* dotv  = ws + 192000;        // 192000
    float* cmean = ws + 384000;        // 192000
    float* cons  = ws + 576000;        // 192000 (row-major, for kD)
    float* consq = ws + 768000;        // 196608 (Q4; 756-SB staging margin)
    float* CSq   = ws + 964608;        // 196608 (Q4; 756-SB store margin)
    float* stepv = ws + 1161216;       // 192000
    float* candf = ws + 1353216;       // 192000
    float* temporal = ws + 1545216;    // 16
    unsigned int* counts = (unsigned int*)(ws + 1545232); // 8 u32

    dim3 g1((TT + 255) / 256, BB);
    k1_colstats<<<g1, 256, 0, stream>>>(mel, ssq, dotv, cmean, counts);
    kA_temporal<<<BB, 256, 0, stream>>>(cmean, temporal);
    kB_cons<<<BT / 256, 256, 0, stream>>>(ssq, dotv, spec, temporal, wts, cons, consq);
    kC_scan16<<<1, 256, 0, stream>>>(consq, CSq);
    kD_prepare<<<BT / 256, 256, 0, stream>>>(cons, CSq, init, stepv, candf, counts);
    k_final<<<BT / 256, 256, 0, stream>>>(init, stepv, candf, counts, (float*)d_out);
}

// Round 21
// 135.514 us; speedup vs baseline: 1.0267x; 1.0267x over previous
//
#include <hip/hip_runtime.h>
#include <cstdint>

#define BB 16
#define MM 128
#define TT 12000
constexpr int BT = BB * TT; // 192000

// Q4-interleaved scan layout: element (row b, pos t), t=4g+j lives at
// q[(g*16 + b)*4 + j]. Group = 256 B (16 rows x 16 B). SB = 4 groups.
// Chunk = 12 SBs = 48 groups = 12288 B. 64 chunks = 768 SBs (750 real).

// K1: per-column stats over the M axis, sequential in m (reference order).
// anti-fma via `#pragma clang fp contract(off)` (proven round 13).
__global__ void k1_colstats(const float* __restrict__ mel,
                            float* __restrict__ ssq,
                            float* __restrict__ dotv,
                            float* __restrict__ cmean,
                            unsigned int* __restrict__ counts) {
    if (blockIdx.x == 0 && blockIdx.y == 0 && threadIdx.x < 8)
        counts[threadIdx.x] = 0u;
    const int b = blockIdx.y;
    const int t = blockIdx.x * blockDim.x + threadIdx.x;
    if (t >= TT) return;
    const float* base = mel + (size_t)b * MM * TT;
    float accd = 0.f, accq = 0.f, accs = 0.f;
    {
#pragma clang fp contract(off)
        for (int m = 0; m < MM; ++m) {
            const float* rowp = base + (size_t)m * TT;
            float cur = rowp[t];
            float prev = (t > 0) ? rowp[t - 1] : 0.f;
            accd += prev * cur;
            accq += cur * cur;
            accs += cur;
        }
    }
    size_t i = (size_t)b * TT + t;
    ssq[i] = accq; dotv[i] = accd; cmean[i] = accs * (1.0f / MM);
}

// kA: temporal = 1 - std(smooth, ddof=1). Row staged to LDS once.
__global__ void kA_temporal(const float* __restrict__ cmean,
                            float* __restrict__ temporal) {
    const int b = blockIdx.x;
    const int tid = threadIdx.x;
    __shared__ __align__(16) float row_s[TT];
    __shared__ float red[256];
    __shared__ float mean_s;
    const float4* c4 = (const float4*)(cmean + (size_t)b * TT);
    float4* r4 = (float4*)row_s;
    for (int i = tid; i < TT / 4; i += 256) r4[i] = c4[i];
    __syncthreads();

    float s = 0.f;
    for (int t = tid; t < TT; t += 256) {
        float v = 0.f;
        int lo = t - 2 < 0 ? 0 : t - 2;
        int hi = t + 2 >= TT ? TT - 1 : t + 2;
        for (int j = lo; j <= hi; ++j) v += row_s[j];
        s += v / 5.0f;
    }
    red[tid] = s; __syncthreads();
    for (int o = 128; o > 0; o >>= 1) {
        if (tid < o) red[tid] += red[tid + o];
        __syncthreads();
    }
    if (tid == 0) mean_s = red[0] / (float)TT;
    __syncthreads();
    float mean = mean_s;
    float ss = 0.f;
    for (int t = tid; t < TT; t += 256) {
        float v = 0.f;
        int lo = t - 2 < 0 ? 0 : t - 2;
        int hi = t + 2 >= TT ? TT - 1 : t + 2;
        for (int j = lo; j <= hi; ++j) v += row_s[j];
        float sm = v / 5.0f - mean;
        ss += sm * sm;
    }
    red[tid] = ss; __syncthreads();
    for (int o = 128; o > 0; o >>= 1) {
        if (tid < o) red[tid] += red[tid + o];
        __syncthreads();
    }
    if (tid == 0) {
        float var = red[0] / (float)(TT - 1);
        temporal[b] = 1.0f - sqrtf(var);
    }
}

// kB: cons — same arithmetic as the passing version; also writes the
// Q4-interleaved copy for the scan (same value, extra store only).
__global__ void kB_cons(const float* __restrict__ ssq,
                        const float* __restrict__ dotv,
                        const float* __restrict__ spec,
                        const float* __restrict__ temporal,
                        const float* __restrict__ wraw,
                        float* __restrict__ cons,
                        float* __restrict__ consq) {
    const int idx = blockIdx.x * 256 + threadIdx.x;
    const int b = idx / TT;
    const int t = idx - b * TT;
    float x0 = wraw[0], x1 = wraw[1], x2 = wraw[2];
    float mx = fmaxf(x0, fmaxf(x1, x2));
    float e0 = expf(x0 - mx), e1 = expf(x1 - mx), e2 = expf(x2 - mx);
    float es = (e0 + e1) + e2;
    float w0 = e0 / es, w1 = e1 / es, w2 = e2 / es;
    float mel_sim, spec_sim;
    if (t == 0) { mel_sim = 0.f; spec_sim = 1.f; }
    else {
        float na = fmaxf(sqrtf(ssq[idx - 1]), 1e-8f);
        float nb = fmaxf(sqrtf(ssq[idx]),     1e-8f);
        float den = na * nb; asm volatile("" : "+v"(den));
        mel_sim = dotv[idx] / den;
        float d = fabsf(spec[idx] - spec[idx - 1]);
        spec_sim = 1.0f / (1.0f + d);
    }
    float pa = w0 * mel_sim;     asm volatile("" : "+v"(pa));
    float pb = w1 * spec_sim;    asm volatile("" : "+v"(pb));
    float pc = w2 * temporal[b]; asm volatile("" : "+v"(pc));
    float c = (pa + pb) + pc;
    cons[idx] = c;
    consq[((t >> 2) * 16 + b) * 4 + (t & 3)] = c;
}

// One SB (4 groups, 16 lanes lockstep): wait vmcnt(44) (48-load pure ring,
// FIFO-exact: drains the 4 oldest = this SB's operands), 16 chained adds
// (bitwise reference order), carry snapshot, 4 ds_writes (CS -> LDS out
// buffer, lgkm — NOT in wave0's vmcnt), 4 prefetch loads 12 SBs ahead,
// self-advancing addresses (+1024 each).
#define SBX(a0,a1,a2,a3, b0,b1,b2,b3, c0,c1,c2,c3, d0,d1,d2,d3) \
    "s_waitcnt vmcnt(44)\n\t" \
    "v_add_f32 v" a0 ", v43, v" a0 "\n\t" \
    "v_add_f32 v" a1 ", v" a0 ", v" a1 "\n\t" \
    "v_add_f32 v" a2 ", v" a1 ", v" a2 "\n\t" \
    "v_add_f32 v" a3 ", v" a2 ", v" a3 "\n\t" \
    "v_add_f32 v" b0 ", v" a3 ", v" b0 "\n\t" \
    "v_add_f32 v" b1 ", v" b0 ", v" b1 "\n\t" \
    "v_add_f32 v" b2 ", v" b1 ", v" b2 "\n\t" \
    "v_add_f32 v" b3 ", v" b2 ", v" b3 "\n\t" \
    "v_add_f32 v" c0 ", v" b3 ", v" c0 "\n\t" \
    "v_add_f32 v" c1 ", v" c0 ", v" c1 "\n\t" \
    "v_add_f32 v" c2 ", v" c1 ", v" c2 "\n\t" \
    "v_add_f32 v" c3 ", v" c2 ", v" c3 "\n\t" \
    "v_add_f32 v" d0 ", v" c3 ", v" d0 "\n\t" \
    "v_add_f32 v" d1 ", v" d0 ", v" d1 "\n\t" \
    "v_add_f32 v" d2 ", v" d1 ", v" d2 "\n\t" \
    "v_add_f32 v" d3 ", v" d2 ", v" d3 "\n\t" \
    "v_mov_b32 v43, v" d3 "\n\t" \
    "ds_write_b128 v44, v[" a0 ":" a3 "] offset:0\n\t" \
    "ds_write_b128 v44, v[" b0 ":" b3 "] offset:256\n\t" \
    "ds_write_b128 v44, v[" c0 ":" c3 "] offset:512\n\t" \
    "ds_write_b128 v44, v[" d0 ":" d3 "] offset:768\n\t" \
    "global_load_dwordx4 v[" a0 ":" a3 "], v40, %0 offset:0\n\t" \
    "global_load_dwordx4 v[" b0 ":" b3 "], v40, %0 offset:256\n\t" \
    "global_load_dwordx4 v[" c0 ":" c3 "], v40, %0 offset:512\n\t" \
    "global_load_dwordx4 v[" d0 ":" d3 "], v40, %0 offset:768\n\t" \
    "v_add_u32 v44, 0x400, v44\n\t" \
    "v_add_u32 v40, 0x400, v40\n\t"

// Prologue SB: issue 4 loads, advance load pointer.
#define PRO(a0,a1,a2,a3, b0,b1,b2,b3, c0,c1,c2,c3, d0,d1,d2,d3) \
    "global_load_dwordx4 v[" a0 ":" a3 "], v40, %0 offset:0\n\t" \
    "global_load_dwordx4 v[" b0 ":" b3 "], v40, %0 offset:256\n\t" \
    "global_load_dwordx4 v[" c0 ":" c3 "], v40, %0 offset:512\n\t" \
    "global_load_dwordx4 v[" d0 ":" d3 "], v40, %0 offset:768\n\t" \
    "v_add_u32 v40, 0x400, v40\n\t"

// 12 ring SB register sets (quads), v48..v239.
#define R0  "48","49","50","51","52","53","54","55","56","57","58","59","60","61","62","63"
#define R1  "64","65","66","67","68","69","70","71","72","73","74","75","76","77","78","79"
#define R2  "80","81","82","83","84","85","86","87","88","89","90","91","92","93","94","95"
#define R3  "96","97","98","99","100","101","102","103","104","105","106","107","108","109","110","111"
#define R4  "112","113","114","115","116","117","118","119","120","121","122","123","124","125","126","127"
#define R5  "128","129","130","131","132","133","134","135","136","137","138","139","140","141","142","143"
#define R6  "144","145","146","147","148","149","150","151","152","153","154","155","156","157","158","159"
#define R7  "160","161","162","163","164","165","166","167","168","169","170","171","172","173","174","175"
#define R8  "176","177","178","179","180","181","182","183","184","185","186","187","188","189","190","191"
#define R9  "192","193","194","195","196","197","198","199","200","201","202","203","204","205","206","207"
#define R10 "208","209","210","211","212","213","214","215","216","217","218","219","220","221","222","223"
#define R11 "224","225","226","227","228","229","230","231","232","233","234","235","236","237","238","239"
#define XP(M, ...) M(__VA_ARGS__)

#define CHUNK12 \
    XP(SBX, R0)  XP(SBX, R1)  XP(SBX, R2)  XP(SBX, R3) \
    XP(SBX, R4)  XP(SBX, R5)  XP(SBX, R6)  XP(SBX, R7) \
    XP(SBX, R8)  XP(SBX, R9)  XP(SBX, R10) XP(SBX, R11) \
    "s_waitcnt lgkmcnt(0)\n\t" \
    "s_barrier\n\t"

// kC: 16-lane SIMT scan, 48-group pure-load global ring (vmcnt(44)/SB),
// CS -> LDS double buffer (12 KB x2), helper waves copy LDS -> CSq per
// chunk behind raw s_barriers (wave0's ring survives — no vmcnt drain).
__global__ void __launch_bounds__(256)
kC_scan16(const float* __restrict__ consq,
          float* __restrict__ CSq) {
    const int tid = threadIdx.x;
    __shared__ __align__(16) float lbuf[6144];   // 2 x 12288 B

    if (tid < BB) {
        uint32_t goff  = (uint32_t)(tid * 16);
        uint32_t laddr = (uint32_t)(uintptr_t)&lbuf[0] + (uint32_t)(tid * 16);
        asm volatile(
            "v_mov_b32 v40, %1\n\t"     // global load byte offset
            "v_mov_b32 v44, %2\n\t"     // LDS write addr (buf base + lane*16)
            "v_mov_b32 v43, 0\n\t"      // carry
            // prologue: fill 48-group ring (12 SBs), v40 ends 12 SBs ahead
            XP(PRO, R0)  XP(PRO, R1)  XP(PRO, R2)  XP(PRO, R3)
            XP(PRO, R4)  XP(PRO, R5)  XP(PRO, R6)  XP(PRO, R7)
            XP(PRO, R8)  XP(PRO, R9)  XP(PRO, R10) XP(PRO, R11)
            "s_mov_b32 s20, 32\n\t"     // 32 x 2 chunks = 64 chunks = 768 SBs
            "3:\n\t"
            CHUNK12                      // chunk even -> lbuf[0..12287]
            CHUNK12                      // chunk odd  -> lbuf[12288..24575]
            "v_add_u32 v44, 0xffffa000, v44\n\t"   // rewind 24576
            "s_sub_u32 s20, s20, 1\n\t"
            "s_cmp_lg_u32 s20, 0\n\t"
            "s_cbranch_scc1 3b\n\t"
            "s_waitcnt vmcnt(0) lgkmcnt(0)\n\t"
            :
            : "s"(consq), "v"(goff), "v"(laddr)
            : "v40", "v43", "v44",
              "v48","v49","v50","v51","v52","v53","v54","v55",
              "v56","v57","v58","v59","v60","v61","v62","v63",
              "v64","v65","v66","v67","v68","v69","v70","v71",
              "v72","v73","v74","v75","v76","v77","v78","v79",
              "v80","v81","v82","v83","v84","v85","v86","v87",
              "v88","v89","v90","v91","v92","v93","v94","v95",
              "v96","v97","v98","v99","v100","v101","v102","v103",
              "v104","v105","v106","v107","v108","v109","v110","v111",
              "v112","v113","v114","v115","v116","v117","v118","v119",
              "v120","v121","v122","v123","v124","v125","v126","v127",
              "v128","v129","v130","v131","v132","v133","v134","v135",
              "v136","v137","v138","v139","v140","v141","v142","v143",
              "v144","v145","v146","v147","v148","v149","v150","v151",
              "v152","v153","v154","v155","v156","v157","v158","v159",
              "v160","v161","v162","v163","v164","v165","v166","v167",
              "v168","v169","v170","v171","v172","v173","v174","v175",
              "v176","v177","v178","v179","v180","v181","v182","v183",
              "v184","v185","v186","v187","v188","v189","v190","v191",
              "v192","v193","v194","v195","v196","v197","v198","v199",
              "v200","v201","v202","v203","v204","v205","v206","v207",
              "v208","v209","v210","v211","v212","v213","v214","v215",
              "v216","v217","v218","v219","v220","v221","v222","v223",
              "v224","v225","v226","v227","v228","v229","v230","v231",
              "v232","v233","v234","v235","v236","v237","v238","v239",
              "s20", "scc", "memory");
    }
    if (tid >= 64) {
        // helper waves: after barrier c, copy chunk c (12 KB) LDS -> global.
        float4* dst4 = (float4*)CSq;
        const float4* b4 = (const float4*)lbuf;
        for (int c = 0; c < 64; ++c) {
            asm volatile("s_barrier" ::: "memory");
            const float4* s4 = b4 + (size_t)(c & 1) * 768;
            float4* d4 = dst4 + (size_t)c * 768;
            for (int i = tid - 64; i < 768; i += 192) d4[i] = s4[i];
        }
    }
}

// kD: candbits + local/step + 5-iter never-done sim. CS read from the
// Q4-interleaved buffer (same values bitwise). Flags instead of counts.
__global__ void kD_prepare(const float* __restrict__ cons,
                           const float* __restrict__ CSq,
                           const float* __restrict__ init,
                           float* __restrict__ stepv,
                           float* __restrict__ candf,
                           unsigned int* __restrict__ counts) {
    const int idx = blockIdx.x * 256 + threadIdx.x;
    const int b = idx / TT;
    const int t = idx - b * TT;
    __shared__ unsigned sflag[5];
    if (threadIdx.x < 5) sflag[threadIdx.x] = 0u;
    __syncthreads();

    int lo = t - 2; if (lo < 0) lo = 0;
    int hi = t + 3; if (hi > TT) hi = TT;
    int uh = hi - 1;
    float csH = CSq[((uh >> 2) * 16 + b) * 4 + (uh & 3)];
    float csL = 0.f;
    if (lo > 0) {
        int ul = lo - 1;
        csL = CSq[((ul >> 2) * 16 + b) * 4 + (ul & 3)];
    }
    float local = (csH - csL) / (float)(hi - lo);
    float dir = (local > 0.7f) ? -0.1f : ((local < 0.4f) ? 0.1f : 0.0f);
    bool interior = (t >= 1) && (t <= TT - 2);
    float step = interior ? dir : 0.0f;
    float g = (t == 0) ? 0.f : fabsf(cons[idx] - cons[idx - 1]);
    float cand = (g > 0.15f) ? 1.f : 0.f;
    float r = init[idx];
    bool nz[5];
#pragma unroll
    for (int j = 0; j < 5; ++j) {
        float adj = (fmaxf(cand, r) > 0.5f) ? step : 0.0f;
        nz[j] = (adj != 0.0f);
        r = fminf(fmaxf(r + adj, 0.0f), 1.0f);
    }
    stepv[idx] = step; candf[idx] = cand;
    const int lane = threadIdx.x & 63;
#pragma unroll
    for (int j = 0; j < 5; ++j) {
        unsigned long long mb = __ballot(nz[j]);
        if (lane == 0 && mb) atomicOr(&sflag[j], 1u);   // LDS-scope, cheap
    }
    __syncthreads();
    if (threadIdx.x < 5 && sflag[threadIdx.x]) counts[threadIdx.x] = 1u;
}

// K_final: freeze at the first iteration whose adjustment flag is 0.
__global__ void k_final(const float* __restrict__ init,
                        const float* __restrict__ stepv,
                        const float* __restrict__ candf,
                        const unsigned int* __restrict__ counts,
                        float* __restrict__ outp) {
    const int idx = blockIdx.x * 256 + threadIdx.x;
    float r = init[idx];
    float step = stepv[idx];
    float cand = candf[idx];
    unsigned c[5];
#pragma unroll
    for (int j = 0; j < 5; ++j) c[j] = counts[j];
#pragma unroll
    for (int j = 0; j < 5; ++j) {
        if (c[j] == 0u) break;
        float adj = (fmaxf(cand, r) > 0.5f) ? step : 0.0f;
        r = fminf(fmaxf(r + adj, 0.0f), 1.0f);
    }
    outp[idx] = r;
}

extern "C" void kernel_launch(void* const* d_in, const int* in_sizes, int n_in,
                              void* d_out, int out_size, void* d_ws, size_t ws_size,
                              hipStream_t stream) {
    const float* mel  = (const float*)d_in[0];
    const float* spec = (const float*)d_in[1];
    const float* init = (const float*)d_in[2];
    const float* wts  = (const float*)d_in[3];

    float* ws = (float*)d_ws;
    float* ssq   = ws;                 // 192000
    float* dotv  = ws + 192000;        // 192000
    float* cmean = ws + 384000;        // 192000
    float* cons  = ws + 576000;        // 192000 (row-major, for kD)
    float* consq = ws + 768000;        // 199680 (Q4; ring-lookahead pad)
    float* CSq   = ws + 967680;        // 196608 (Q4; 768-SB store region)
    float* stepv = ws + 1164288;       // 192000
    float* candf = ws + 1356288;       // 192000
    float* temporal = ws + 1548288;    // 16
    unsigned int* counts = (unsigned int*)(ws + 1548304); // 8 u32

    dim3 g1((TT + 255) / 256, BB);
    k1_colstats<<<g1, 256, 0, stream>>>(mel, ssq, dotv, cmean, counts);
    kA_temporal<<<BB, 256, 0, stream>>>(cmean, temporal);
    kB_cons<<<BT / 256, 256, 0, stream>>>(ssq, dotv, spec, temporal, wts, cons, consq);
    kC_scan16<<<1, 256, 0, stream>>>(consq, CSq);
    kD_prepare<<<BT / 256, 256, 0, stream>>>(cons, CSq, init, stepv, candf, counts);
    k_final<<<BT / 256, 256, 0, stream>>>(init, stepv, candf, counts, (float*)d_out);
}